// Round 2
// baseline (79.803 us; speedup 1.0000x reference)
//
#include <hip/hip_runtime.h>

#define BATCH 262144
#define BLOCK 256

struct c2f { float re, im; };

__device__ __forceinline__ c2f cmul(c2f a, c2f b){
    return { a.re*b.re - a.im*b.im, a.re*b.im + a.im*b.re };
}
__device__ __forceinline__ c2f cmulc(c2f a, c2f b){  // a * conj(b)
    return { a.re*b.re + a.im*b.im, a.im*b.re - a.re*b.im };
}
// SU(2) matrices stored as (alpha, beta): M = [[a, b], [-conj(b), conj(a)]]
__device__ __forceinline__ void su2mul(c2f a1, c2f b1, c2f a2, c2f b2, c2f& ao, c2f& bo){
    c2f t1 = cmul(a1, a2), t2 = cmulc(b1, b2);
    ao = { t1.re - t2.re, t1.im - t2.im };
    c2f t3 = cmul(a1, b2), t4 = cmulc(b1, a2);
    bo = { t3.re + t4.re, t3.im + t4.im };
}
// CZ diagonal sign: -1 iff parity of adjacent-pair AND products is odd.
// qubit 0 = MSB (bit 3). Pairs (0,1),(1,2),(2,3),(0,3).
__device__ __forceinline__ int czneg(int s){
    int b0 = (s >> 3) & 1, b1 = (s >> 2) & 1, b2 = (s >> 1) & 1, b3 = s & 1;
    return (b0 & b1) ^ (b1 & b2) ^ (b2 & b3) ^ (b0 & b3);
}

__global__ __launch_bounds__(BLOCK) void vqc_kernel(
    const float* __restrict__ x,      // (BATCH,4) f32
    const float* __restrict__ theta,  // 48 f32
    const float* __restrict__ lmbd,   // 12 f32
    float* __restrict__ out)          // (BATCH,4) f32
{
    // --- per-block precompute of batch-independent SU(2) factors ---
    __shared__ float2 sU[4][4][2];   // [param layer 0..3][qubit][alpha,beta]
    __shared__ float2 sA[3][4][2];   // A^(0)=U1*W, A^(1)=U2*W, A^(2)=W  (W=U3)
    __shared__ float2 sPsi0[16];     // CZ * (tensor U^(0)) |0>
    __shared__ float  sL[12];        // lmbd

    const int tid = threadIdx.x;

    if (tid < 16) {
        int l = tid >> 2, q = tid & 3;
        float t0 = 0.5f * theta[(l * 4 + q) * 3 + 0];
        float t1 = 0.5f * theta[(l * 4 + q) * 3 + 1];
        float t2 = 0.5f * theta[(l * 4 + q) * 3 + 2];
        float c0, s0, c1, s1, c2v, s2v;
        __sincosf(t0, &s0, &c0);
        __sincosf(t1, &s1, &c1);
        __sincosf(t2, &s2v, &c2v);
        // RY(t1)*RX(t0): alpha = c1 c0 + i s1 s0 ; beta = -s1 c0 - i c1 s0
        c2f aP = { c1 * c0, s1 * s0 };
        c2f bP = { -s1 * c0, -c1 * s0 };
        // RZ(t2)*P: multiply (alpha,beta) by e^{-i t2/2}
        c2f ph = { c2v, -s2v };
        c2f aU = cmul(ph, aP);
        c2f bU = cmul(ph, bP);
        sU[l][q][0] = make_float2(aU.re, aU.im);
        sU[l][q][1] = make_float2(bU.re, bU.im);
    }
    if (tid < 12) sL[tid] = lmbd[tid];
    __syncthreads();

    if (tid < 12) {
        int k = tid >> 2, q = tid & 3;
        c2f aW = { sU[3][q][0].x, sU[3][q][0].y };
        c2f bW = { sU[3][q][1].x, sU[3][q][1].y };
        c2f aA = aW, bA = bW;
        if (k < 2) {
            c2f aN = { sU[k + 1][q][0].x, sU[k + 1][q][0].y };
            c2f bN = { sU[k + 1][q][1].x, sU[k + 1][q][1].y };
            su2mul(aN, bN, aW, bW, aA, bA);   // U^(k+1) * W
        }
        sA[k][q][0] = make_float2(aA.re, aA.im);
        sA[k][q][1] = make_float2(bA.re, bA.im);
    }
    if (tid >= 16 && tid < 32) {
        int s = tid - 16;
        c2f v = { 1.f, 0.f };
        #pragma unroll
        for (int q = 0; q < 4; ++q) {
            int bit = (s >> (3 - q)) & 1;
            // column 0 of U: bit0 -> alpha ; bit1 -> -conj(beta)
            c2f a = { sU[0][q][0].x, sU[0][q][0].y };
            c2f b = { sU[0][q][1].x, sU[0][q][1].y };
            c2f e = bit ? c2f{ -b.re, b.im } : a;
            v = cmul(v, e);
        }
        if (czneg(s)) { v.re = -v.re; v.im = -v.im; }
        sPsi0[s] = make_float2(v.re, v.im);
    }
    __syncthreads();

    // --- per-thread statevector simulation ---
    const int b = blockIdx.x * BLOCK + tid;
    float4 xr = ((const float4*)x)[b];
    float xv[4] = { xr.x, xr.y, xr.z, xr.w };

    float prr[16], pii[16];
    #pragma unroll
    for (int s = 0; s < 16; ++s) { float2 v = sPsi0[s]; prr[s] = v.x; pii[s] = v.y; }

    #pragma unroll
    for (int k = 0; k < 3; ++k) {
        float ch[4], sh[4];
        #pragma unroll
        for (int q = 0; q < 4; ++q) {
            float h = 0.5f * sL[k * 4 + q] * xv[q];
            __sincosf(h, &sh[q], &ch[q]);
        }
        #pragma unroll
        for (int q = 0; q < 4; ++q) {
            float c = ch[q], s = sh[q];
            int zq = q >> 1;                 // zang = (a0,a0,a1,a1)
            float cz = ch[zq], sz = sh[zq];
            float cc = c * c, ss = s * s, cs = c * s;
            // V = RZ(z)*RY(a)*RX(a) in SU2 (alpha,beta) form
            c2f aV = { cc * cz + ss * sz, ss * cz - cc * sz };
            c2f bV = { -cs * (cz + sz), -cs * (cz - sz) };
            float2 fa = sA[k][q][0], fb = sA[k][q][1];
            c2f aA = { fa.x, fa.y }, bA = { fb.x, fb.y };
            c2f aM, bM;
            su2mul(aA, bA, aV, bV, aM, bM);  // M = A^(k) * V
            const int R = 8 >> q;
            #pragma unroll
            for (int g = 0; g < 8; ++g) {
                int low = g & (R - 1);
                int s0i = ((g - low) << 1) | low;
                int s1i = s0i + R;
                float p0r = prr[s0i], p0i = pii[s0i];
                float p1r = prr[s1i], p1i = pii[s1i];
                prr[s0i] =  aM.re * p0r - aM.im * p0i + bM.re * p1r - bM.im * p1i;
                pii[s0i] =  aM.re * p0i + aM.im * p0r + bM.re * p1i + bM.im * p1r;
                prr[s1i] = -bM.re * p0r - bM.im * p0i + aM.re * p1r + aM.im * p1i;
                pii[s1i] = -bM.re * p0i + bM.im * p0r + aM.re * p1i - aM.im * p1r;
            }
        }
        if (k < 2) {
            #pragma unroll
            for (int s = 0; s < 16; ++s) {
                if (czneg(s)) { prr[s] = -prr[s]; pii[s] = -pii[s]; }
            }
        }
    }

    // probs and Z expectations (qubit j reads bit (3-j))
    float o0 = 0.f, o1 = 0.f, o2 = 0.f, o3 = 0.f;
    #pragma unroll
    for (int s = 0; s < 16; ++s) {
        float p = prr[s] * prr[s] + pii[s] * pii[s];
        o0 += ((s >> 3) & 1) ? -p : p;
        o1 += ((s >> 2) & 1) ? -p : p;
        o2 += ((s >> 1) & 1) ? -p : p;
        o3 += ((s >> 0) & 1) ? -p : p;
    }
    float4 ov;
    ov.x = o0; ov.y = o1; ov.z = o2; ov.w = o3;
    ((float4*)out)[b] = ov;
}

extern "C" void kernel_launch(void* const* d_in, const int* in_sizes, int n_in,
                              void* d_out, int out_size, void* d_ws, size_t ws_size,
                              hipStream_t stream) {
    const float* x     = (const float*)d_in[0];
    const float* theta = (const float*)d_in[1];
    const float* lmbd  = (const float*)d_in[2];
    float* out = (float*)d_out;
    vqc_kernel<<<dim3(BATCH / BLOCK), dim3(BLOCK), 0, stream>>>(x, theta, lmbd, out);
}